// Round 1
// baseline (305.466 us; speedup 1.0000x reference)
//
#include <hip/hip_runtime.h>

// Problem constants from the reference
constexpr int B_ = 32;
constexpr int S_ = 2048;
constexpr int F_ = 512;
constexpr int ROWS = B_ * S_;          // 65536 rows of length F=512
constexpr int WAVES_PER_BLOCK = 4;     // 256 threads = 4 waves, 1 row per wave

// out = one_hot(argmax_F(logits + gumbel)) per row.
// (The reference's softmax -> straight-through -> top_k -> scatter pipeline is
//  the identity on the one-hot mask: non-argmax entries are exactly +0.0 and the
//  K smallest entries selected by top_k are all already-zero positions.)
__global__ __launch_bounds__(256) void gumbel_hard_onehot_kernel(
    const float* __restrict__ logits,
    const float* __restrict__ gumbel,
    float* __restrict__ out)
{
    const int lane = threadIdx.x & 63;
    const int wave = threadIdx.x >> 6;
    const int row  = blockIdx.x * WAVES_PER_BLOCK + wave;
    if (row >= ROWS) return;

    const size_t row_off = (size_t)row * F_;
    const float4* __restrict__ lg = (const float4*)(logits + row_off);
    const float4* __restrict__ gm = (const float4*)(gumbel + row_off);
    float4* __restrict__ op = (float4*)(out + row_off);

    // 512 floats / row = 128 float4. Lane i handles float4 slots i and i+64.
    float4 a0 = lg[lane];
    float4 a1 = lg[lane + 64];
    float4 b0 = gm[lane];
    float4 b1 = gm[lane + 64];

    float v[8];
    v[0] = a0.x + b0.x; v[1] = a0.y + b0.y; v[2] = a0.z + b0.z; v[3] = a0.w + b0.w;
    v[4] = a1.x + b1.x; v[5] = a1.y + b1.y; v[6] = a1.z + b1.z; v[7] = a1.w + b1.w;

    const int base0 = lane * 4;        // element indices of v[0..3]
    const int base1 = 256 + lane * 4;  // element indices of v[4..7]

    // Local max, first-index tie-break via strict '>' in increasing index order.
    float best = v[0];
    int   bidx = base0;
#pragma unroll
    for (int j = 1; j < 4; ++j) {
        if (v[j] > best) { best = v[j]; bidx = base0 + j; }
    }
#pragma unroll
    for (int j = 0; j < 4; ++j) {
        if (v[4 + j] > best) { best = v[4 + j]; bidx = base1 + j; }
    }

    // Wave-wide (64-lane) butterfly argmax; tie -> smaller index.
#pragma unroll
    for (int off = 32; off > 0; off >>= 1) {
        float ov = __shfl_xor(best, off, 64);
        int   oi = __shfl_xor(bidx, off, 64);
        if (ov > best || (ov == best && oi < bidx)) { best = ov; bidx = oi; }
    }
    // All lanes now agree on bidx = argmax element index within the row.

    float4 z0, z1;
    z0.x = (base0 + 0 == bidx) ? 1.0f : 0.0f;
    z0.y = (base0 + 1 == bidx) ? 1.0f : 0.0f;
    z0.z = (base0 + 2 == bidx) ? 1.0f : 0.0f;
    z0.w = (base0 + 3 == bidx) ? 1.0f : 0.0f;
    z1.x = (base1 + 0 == bidx) ? 1.0f : 0.0f;
    z1.y = (base1 + 1 == bidx) ? 1.0f : 0.0f;
    z1.z = (base1 + 2 == bidx) ? 1.0f : 0.0f;
    z1.w = (base1 + 3 == bidx) ? 1.0f : 0.0f;

    op[lane]      = z0;
    op[lane + 64] = z1;
}

extern "C" void kernel_launch(void* const* d_in, const int* in_sizes, int n_in,
                              void* d_out, int out_size, void* d_ws, size_t ws_size,
                              hipStream_t stream) {
    const float* logits = (const float*)d_in[0];
    const float* gumbel = (const float*)d_in[1];
    float* out = (float*)d_out;

    const int grid = ROWS / WAVES_PER_BLOCK;  // 16384 blocks x 256 threads
    gumbel_hard_onehot_kernel<<<grid, 256, 0, stream>>>(logits, gumbel, out);
}